// Round 1
// baseline (423.366 us; speedup 1.0000x reference)
//
#include <hip/hip_runtime.h>
#include <hip/hip_bf16.h>
#include <cstdint>

// Problem constants: B=4, T=512, S=512, V=8, M=2, K=4, F=1, Hqk=32, Hv=32, C=256
#define BB 4
#define TT 512
#define SS 512
#define VV 8
#define MM 2
#define KK 4
#define HQK 32
#define HV 32
#define CC 256
// rows of the "token" matrices: B*T*V
#define NROWS (BB * TT * VV)   // 16384

// ---------------- pack Wq|Wk|Wv into Wcat (256 x 512, row-major c-major) ----
__global__ __launch_bounds__(256) void pack_w_kernel(const float* __restrict__ Wq,
                                                     const float* __restrict__ Wk,
                                                     const float* __restrict__ Wv,
                                                     float* __restrict__ Wcat) {
  int idx = blockIdx.x * 256 + threadIdx.x;  // 0 .. 256*512-1
  int c = idx >> 9;
  int j = idx & 511;
  float val;
  if (j < 256)      val = Wq[c * 256 + j];           // q cols: j = m*128 + k*32 + h
  else if (j < 384) val = Wk[c * 128 + (j - 256)];   // k cols: k*32 + h
  else              val = Wv[c * 128 + (j - 384)];   // v cols: k*32 + h
  Wcat[idx] = val;
}

// ---------------- GEMM: C(M x N) = A(M x 256) * W(256 x N), all row-major ---
// 64x64 tile, 256 threads, 4x4 microtile, K-step 16.
__global__ __launch_bounds__(256) void gemm_f32(const float* __restrict__ A,
                                                const float* __restrict__ W,
                                                float* __restrict__ C, int N) {
  __shared__ float As[16][64];  // [kk][row]
  __shared__ float Ws[16][64];  // [kk][col]
  const int tid = threadIdx.x;
  const int tx = tid & 15;        // col group
  const int ty = tid >> 4;        // row group
  const int bm = blockIdx.x * 64;
  const int bn = blockIdx.y * 64;

  float acc[4][4] = {{0.f}};

  for (int k0 = 0; k0 < 256; k0 += 16) {
    // stage A: 64 rows x 16 k  (vary kk fastest for coalescing)
#pragma unroll
    for (int l = tid; l < 64 * 16; l += 256) {
      int i = l >> 4, kk = l & 15;
      As[kk][i] = A[(bm + i) * 256 + k0 + kk];
    }
    // stage W: 16 k x 64 cols (vary col fastest)
#pragma unroll
    for (int l = tid; l < 16 * 64; l += 256) {
      int kk = l >> 6, j = l & 63;
      Ws[kk][j] = W[(k0 + kk) * N + bn + j];
    }
    __syncthreads();
#pragma unroll
    for (int kk = 0; kk < 16; ++kk) {
      float4 av = *(const float4*)&As[kk][ty * 4];
      float4 bv = *(const float4*)&Ws[kk][tx * 4];
      const float a[4] = {av.x, av.y, av.z, av.w};
      const float b[4] = {bv.x, bv.y, bv.z, bv.w};
#pragma unroll
      for (int ia = 0; ia < 4; ++ia)
#pragma unroll
        for (int ib = 0; ib < 4; ++ib) acc[ia][ib] += a[ia] * b[ib];
    }
    __syncthreads();
  }
#pragma unroll
  for (int ia = 0; ia < 4; ++ia) {
    float4 r = make_float4(acc[ia][0], acc[ia][1], acc[ia][2], acc[ia][3]);
    *(float4*)&C[(size_t)(bm + ty * 4 + ia) * N + bn + tx * 4] = r;
  }
}

// ---------------- fused masked attention --------------------------------
// qkv rows: r = (b*T + t)*V + v, 512 cols: [0,256) q (m*128+k*32+h),
// [256,384) k (k*32+h), [384,512) v (k*32+h).
// One thread per (t_local, m, k); block = (t0, v, b); 32 t-rows per block.
__global__ __launch_bounds__(256) void attn_kernel(const float* __restrict__ qkv,
                                                   const int* __restrict__ mask,
                                                   float* __restrict__ att) {
  const int t0 = blockIdx.x * 32;
  const int v = blockIdx.y;
  const int b = blockIdx.z;
  const int tid = threadIdx.x;
  const int tl = tid >> 3;        // 0..31 (t row within block)
  const int m = (tid >> 2) & 1;   // 0..1
  const int k = tid & 3;          // 0..3
  const int t = t0 + tl;

  __shared__ float Ks[32][128];
  __shared__ float Vs[32][128];
  __shared__ int Ms[32][33];  // padded: lanes read stride-33 -> conflict-free

  // q row in registers (32 floats, 128B contiguous per thread)
  float q[32];
  const float* qrow = qkv + ((size_t)((b * TT + t) * VV + v)) * 512 + m * 128 + k * 32;
#pragma unroll
  for (int h = 0; h < 32; ++h) q[h] = qrow[h];

  float acc[32] = {};
  float m_run = -INFINITY;
  float l_run = 0.f;
  const float scale = 0.17677669529663687f;  // 1/sqrt(32)

  for (int s0 = 0; s0 < SS; s0 += 32) {
    __syncthreads();  // protect previous tile's reads
    // stage K/V tile: 32 s-rows x 128
#pragma unroll
    for (int l = tid; l < 32 * 128; l += 256) {
      int si = l >> 7, jj = l & 127;
      const float* src = qkv + ((size_t)((b * TT + (s0 + si)) * VV + v)) * 512;
      Ks[si][jj] = src[256 + jj];
      Vs[si][jj] = src[384 + jj];
    }
    // stage mask tile: 32 t-rows x 32 s
#pragma unroll
    for (int l = tid; l < 32 * 32; l += 256) {
      int i = l >> 5, j = l & 31;
      Ms[i][j] = mask[((size_t)(b * TT + t0 + i)) * SS + s0 + j];
    }
    __syncthreads();

    for (int si = 0; si < 32; ++si) {
      if (Ms[tl][si]) {
        const float* kp = &Ks[si][k * 32];
        float dot = 0.f;
#pragma unroll
        for (int h = 0; h < 32; ++h) dot += q[h] * kp[h];
        dot *= scale;
        float p;
        if (dot > m_run) {
          float corr = __expf(m_run - dot);  // first hit: exp(-inf)=0
          l_run *= corr;
#pragma unroll
          for (int h = 0; h < 32; ++h) acc[h] *= corr;
          m_run = dot;
          p = 1.0f;
        } else {
          p = __expf(dot - m_run);
        }
        l_run += p;
        const float* vp = &Vs[si][k * 32];
#pragma unroll
        for (int h = 0; h < 32; ++h) acc[h] += p * vp[h];
      }
    }
  }

  const float inv = 1.0f / l_run;  // mask[...,0] is always True -> l_run > 0
  float* dst = att + ((size_t)((b * TT + t) * VV + v)) * 256 + m * 128 + k * 32;
#pragma unroll
  for (int h = 0; h < 32; ++h) dst[h] = acc[h] * inv;
}

extern "C" void kernel_launch(void* const* d_in, const int* in_sizes, int n_in,
                              void* d_out, int out_size, void* d_ws, size_t ws_size,
                              hipStream_t stream) {
  const float* x = (const float*)d_in[0];
  const float* Wq = (const float*)d_in[1];
  const float* Wk = (const float*)d_in[2];
  const float* Wv = (const float*)d_in[3];
  const float* Wout = (const float*)d_in[4];
  const int* mask = (const int*)d_in[5];
  float* out = (float*)d_out;

  // workspace layout (floats): Wcat 256*512 | qkv 16384*512 | att 16384*256
  float* ws = (float*)d_ws;
  float* Wcat = ws;
  float* qkv = Wcat + 256 * 512;
  float* att = qkv + (size_t)NROWS * 512;
  // total = 0.5 + 32 + 16 MB ~= 50.9 MB of d_ws

  pack_w_kernel<<<512, 256, 0, stream>>>(Wq, Wk, Wv, Wcat);
  gemm_f32<<<dim3(NROWS / 64, 512 / 64), 256, 0, stream>>>(x, Wcat, qkv, 512);
  attn_kernel<<<dim3(TT / 32, VV, BB), 256, 0, stream>>>(qkv, mask, att);
  gemm_f32<<<dim3(NROWS / 64, 256 / 64), 256, 0, stream>>>(att, Wout, out, 256);
}

// Round 2
// 195.174 us; speedup vs baseline: 2.1692x; 2.1692x over previous
//
#include <hip/hip_runtime.h>
#include <hip/hip_bf16.h>
#include <cstdint>

// Problem constants: B=4, T=512, S=512, V=8, M=2, K=4, F=1, Hqk=32, Hv=32, C=256
#define BB 4
#define TT 512
#define SS 512
#define VV 8
#define CC 256
#define NROWS (BB * TT * VV)   // 16384

typedef __attribute__((ext_vector_type(8))) short bf16x8;
typedef __attribute__((ext_vector_type(4))) float f32x4;

static __device__ __forceinline__ short f2bf(float f) {
  union { float f; unsigned u; } x; x.f = f;
  unsigned r = x.u + 0x7FFFu + ((x.u >> 16) & 1u);  // RNE
  return (short)(r >> 16);
}

// ---------------- pack Wq|Wk|Wv into Wcat (256 x 512, row-major c-major) ----
__global__ __launch_bounds__(256) void pack_w_kernel(const float* __restrict__ Wq,
                                                     const float* __restrict__ Wk,
                                                     const float* __restrict__ Wv,
                                                     float* __restrict__ Wcat) {
  int idx = blockIdx.x * 256 + threadIdx.x;
  int c = idx >> 9;
  int j = idx & 511;
  float val;
  if (j < 256)      val = Wq[c * 256 + j];
  else if (j < 384) val = Wk[c * 128 + (j - 256)];
  else              val = Wv[c * 128 + (j - 384)];
  Wcat[idx] = val;
}

// ---------------- GEMM: C(M x N) = A(M x 256) * W(256 x N), all row-major ---
__global__ __launch_bounds__(256) void gemm_f32(const float* __restrict__ A,
                                                const float* __restrict__ W,
                                                float* __restrict__ C, int N) {
  __shared__ float As[16][64];
  __shared__ float Ws[16][64];
  const int tid = threadIdx.x;
  const int tx = tid & 15;
  const int ty = tid >> 4;
  const int bm = blockIdx.x * 64;
  const int bn = blockIdx.y * 64;

  float acc[4][4] = {{0.f}};

  for (int k0 = 0; k0 < 256; k0 += 16) {
#pragma unroll
    for (int l = tid; l < 64 * 16; l += 256) {
      int i = l >> 4, kk = l & 15;
      As[kk][i] = A[(bm + i) * 256 + k0 + kk];
    }
#pragma unroll
    for (int l = tid; l < 16 * 64; l += 256) {
      int kk = l >> 6, j = l & 63;
      Ws[kk][j] = W[(k0 + kk) * N + bn + j];
    }
    __syncthreads();
#pragma unroll
    for (int kk = 0; kk < 16; ++kk) {
      float4 av = *(const float4*)&As[kk][ty * 4];
      float4 bv = *(const float4*)&Ws[kk][tx * 4];
      const float a[4] = {av.x, av.y, av.z, av.w};
      const float b[4] = {bv.x, bv.y, bv.z, bv.w};
#pragma unroll
      for (int ia = 0; ia < 4; ++ia)
#pragma unroll
        for (int ib = 0; ib < 4; ++ib) acc[ia][ib] += a[ia] * b[ib];
    }
    __syncthreads();
  }
#pragma unroll
  for (int ia = 0; ia < 4; ++ia) {
    float4 r = make_float4(acc[ia][0], acc[ia][1], acc[ia][2], acc[ia][3]);
    *(float4*)&C[(size_t)(bm + ty * 4 + ia) * N + bn + tx * 4] = r;
  }
}

// ---------------- MFMA flash attention ------------------------------------
// Block: (t-tile of 64, v*4+k, b). 4 waves; wave w owns t-rows t0+16w..+15
// for BOTH m heads (they share K/V). qkv row r=(b*T+t)*V+v; cols:
// q at m*128+k*32+h, k at 256+k*32+h, v at 384+k*32+h.
__global__ __launch_bounds__(256) void attn_mfma(const float* __restrict__ qkv,
                                                 const int* __restrict__ mask,
                                                 float* __restrict__ att) {
  const int t0 = blockIdx.x * 64;
  const int v  = blockIdx.y >> 2;
  const int k  = blockIdx.y & 3;
  const int b  = blockIdx.z;
  const int tid = threadIdx.x;
  const int w  = tid >> 6;       // wave 0..3
  const int ln = tid & 63;
  const int gq = ln >> 4;        // lane group 0..3
  const int tr = ln & 15;        // 0..15

  __shared__ short Kt[64][40];      // [s][h] bf16, pad 40 (80B rows -> 2-way max)
  __shared__ short Vt[32][72];      // [h][s] bf16 transposed, pad 72
  __shared__ short Pt[4][16][72];   // per-wave P tile [t][s], pad 72

  // Q fragments: A-layout lane holds Q[t=tr][h=gq*8..+7]
  bf16x8 qf[2];
  {
    const float* qp = qkv + ((size_t)((b*TT + t0 + w*16 + tr)*VV + v))*512 + k*32 + gq*8;
#pragma unroll
    for (int m = 0; m < 2; ++m) {
      float4 q0 = *(const float4*)(qp + m*128);
      float4 q1 = *(const float4*)(qp + m*128 + 4);
      bf16x8 t;
      t[0]=f2bf(q0.x); t[1]=f2bf(q0.y); t[2]=f2bf(q0.z); t[3]=f2bf(q0.w);
      t[4]=f2bf(q1.x); t[5]=f2bf(q1.y); t[6]=f2bf(q1.z); t[7]=f2bf(q1.w);
      qf[m] = t;
    }
  }

  f32x4 acc_o[2][2] = {};           // [m][h-half], rows 4*gq+r, col tr
  float m_run[2][4], l_run[2][4];
#pragma unroll
  for (int m = 0; m < 2; ++m)
#pragma unroll
    for (int r = 0; r < 4; ++r) { m_run[m][r] = -1e30f; l_run[m][r] = 0.f; }
  const float scale = 0.17677669529663687f;  // 1/sqrt(32)

  const int srow = tid >> 2;        // 0..63
  const int hg = (tid & 3) * 8;     // 0,8,16,24

  for (int s0 = 0; s0 < SS; s0 += 64) {
    __syncthreads();
    // stage K (row-major) and V (transposed) as bf16
    {
      const float* src = qkv + ((size_t)((b*TT + s0 + srow)*VV + v))*512 + 256 + k*32 + hg;
      float4 k0 = *(const float4*)src;
      float4 k1 = *(const float4*)(src + 4);
      float4 v0 = *(const float4*)(src + 128);
      float4 v1 = *(const float4*)(src + 132);
      bf16x8 kv;
      kv[0]=f2bf(k0.x); kv[1]=f2bf(k0.y); kv[2]=f2bf(k0.z); kv[3]=f2bf(k0.w);
      kv[4]=f2bf(k1.x); kv[5]=f2bf(k1.y); kv[6]=f2bf(k1.z); kv[7]=f2bf(k1.w);
      *(bf16x8*)&Kt[srow][hg] = kv;
      float vv[8] = {v0.x, v0.y, v0.z, v0.w, v1.x, v1.y, v1.z, v1.w};
#pragma unroll
      for (int j = 0; j < 8; ++j) Vt[hg + j][srow] = f2bf(vv[j]);
    }
    __syncthreads();

    // fragments from LDS (aligned b128, padded strides)
    bf16x8 kf[4], vf[2][2];
#pragma unroll
    for (int st = 0; st < 4; ++st) kf[st] = *(const bf16x8*)&Kt[st*16 + tr][gq*8];
#pragma unroll
    for (int sh = 0; sh < 2; ++sh)
#pragma unroll
      for (int hh = 0; hh < 2; ++hh)
        vf[sh][hh] = *(const bf16x8*)&Vt[hh*16 + tr][sh*32 + gq*8];

    // logits: D[t][s], rows 4*gq+r, cols tr
    f32x4 lac[2][4];
#pragma unroll
    for (int m = 0; m < 2; ++m)
#pragma unroll
      for (int st = 0; st < 4; ++st) {
        f32x4 z = {0.f, 0.f, 0.f, 0.f};
        lac[m][st] = __builtin_amdgcn_mfma_f32_16x16x32_bf16(qf[m], kf[st], z, 0, 0, 0);
      }

    // mask tile: lane needs mask[t=4*gq+r][s=st*16+tr] (L2-resident, 4MB total)
    int msk[4][4];
    {
      const int* mrow = mask + ((size_t)(b*TT + t0 + w*16 + 4*gq))*SS + s0 + tr;
#pragma unroll
      for (int r = 0; r < 4; ++r)
#pragma unroll
        for (int st = 0; st < 4; ++st)
          msk[st][r] = mrow[(size_t)r*SS + st*16];
    }

#pragma unroll
    for (int m = 0; m < 2; ++m) {
      float pl[4][4];
#pragma unroll
      for (int st = 0; st < 4; ++st)
#pragma unroll
        for (int r = 0; r < 4; ++r)
          pl[st][r] = msk[st][r] ? lac[m][st][r] * scale : -INFINITY;

      float cm[4], mnew[4], corr[4], rs[4];
#pragma unroll
      for (int r = 0; r < 4; ++r) {
        cm[r] = fmaxf(fmaxf(pl[0][r], pl[1][r]), fmaxf(pl[2][r], pl[3][r]));
#pragma unroll
        for (int off = 1; off < 16; off <<= 1) cm[r] = fmaxf(cm[r], __shfl_xor(cm[r], off));
        mnew[r] = fmaxf(m_run[m][r], cm[r]);          // >= -1e30, never -inf
        corr[r] = __expf(m_run[m][r] - mnew[r]);
      }
#pragma unroll
      for (int st = 0; st < 4; ++st)
#pragma unroll
        for (int r = 0; r < 4; ++r)
          pl[st][r] = __expf(pl[st][r] - mnew[r]);    // masked: exp(-inf)=0
#pragma unroll
      for (int r = 0; r < 4; ++r) {
        rs[r] = pl[0][r] + pl[1][r] + pl[2][r] + pl[3][r];
#pragma unroll
        for (int off = 1; off < 16; off <<= 1) rs[r] += __shfl_xor(rs[r], off);
        l_run[m][r] = l_run[m][r] * corr[r] + rs[r];
        m_run[m][r] = mnew[r];
      }
#pragma unroll
      for (int hh = 0; hh < 2; ++hh)
#pragma unroll
        for (int r = 0; r < 4; ++r)
          acc_o[m][hh][r] *= corr[r];

      // C-layout -> A-layout via per-wave LDS round-trip
#pragma unroll
      for (int st = 0; st < 4; ++st)
#pragma unroll
        for (int r = 0; r < 4; ++r)
          Pt[w][4*gq + r][st*16 + tr] = f2bf(pl[st][r]);
      // wave-local write->read: compiler inserts lgkmcnt, no barrier needed
#pragma unroll
      for (int sh = 0; sh < 2; ++sh) {
        bf16x8 pf = *(const bf16x8*)&Pt[w][tr][sh*32 + gq*8];
#pragma unroll
        for (int hh = 0; hh < 2; ++hh)
          acc_o[m][hh] = __builtin_amdgcn_mfma_f32_16x16x32_bf16(pf, vf[sh][hh], acc_o[m][hh], 0, 0, 0);
      }
    }
  }

  // epilogue: rows 4*gq+r, col tr (+16 for second half)
#pragma unroll
  for (int m = 0; m < 2; ++m)
#pragma unroll
    for (int r = 0; r < 4; ++r) {
      float inv = 1.f / l_run[m][r];   // mask[...,0]=True -> l_run > 0
      float* dst = att + ((size_t)((b*TT + t0 + w*16 + 4*gq + r)*VV + v))*256
                 + m*128 + k*32 + tr;
      dst[0]  = acc_o[m][0][r] * inv;
      dst[16] = acc_o[m][1][r] * inv;
    }
}

extern "C" void kernel_launch(void* const* d_in, const int* in_sizes, int n_in,
                              void* d_out, int out_size, void* d_ws, size_t ws_size,
                              hipStream_t stream) {
  const float* x = (const float*)d_in[0];
  const float* Wq = (const float*)d_in[1];
  const float* Wk = (const float*)d_in[2];
  const float* Wv = (const float*)d_in[3];
  const float* Wout = (const float*)d_in[4];
  const int* mask = (const int*)d_in[5];
  float* out = (float*)d_out;

  float* ws = (float*)d_ws;
  float* Wcat = ws;
  float* qkv = Wcat + 256 * 512;
  float* att = qkv + (size_t)NROWS * 512;

  pack_w_kernel<<<512, 256, 0, stream>>>(Wq, Wk, Wv, Wcat);
  gemm_f32<<<dim3(NROWS / 64, 512 / 64), 256, 0, stream>>>(x, Wcat, qkv, 512);
  attn_mfma<<<dim3(TT / 64, VV * 4, BB), 256, 0, stream>>>(qkv, mask, att);
  gemm_f32<<<dim3(NROWS / 64, 256 / 64), 256, 0, stream>>>(att, Wout, out, 256);
}

// Round 3
// 92.030 us; speedup vs baseline: 4.6003x; 2.1208x over previous
//
#include <hip/hip_runtime.h>
#include <hip/hip_bf16.h>
#include <cstdint>

// Problem constants: B=4, T=512, S=512, V=8, M=2, K=4, F=1, Hqk=32, Hv=32, C=256
#define BB 4
#define TT 512
#define SS 512
#define VV 8
#define NROWS (BB * TT * VV)   // 16384

typedef __attribute__((ext_vector_type(8))) short bf16x8;
typedef __attribute__((ext_vector_type(4))) float f32x4;

static __device__ __forceinline__ short f2bf(float f) {
  union { float f; unsigned u; } x; x.f = f;
  unsigned r = x.u + 0x7FFFu + ((x.u >> 16) & 1u);  // RNE
  return (short)(r >> 16);
}

// ---------------- fp32 -> bf16 bulk convert (8 elems/thread) ---------------
__global__ __launch_bounds__(256) void cvt_bf16_kernel(const float* __restrict__ in,
                                                       short* __restrict__ out) {
  int i = blockIdx.x * 256 + threadIdx.x;
  float4 a = ((const float4*)in)[2 * i];
  float4 b = ((const float4*)in)[2 * i + 1];
  bf16x8 o;
  o[0]=f2bf(a.x); o[1]=f2bf(a.y); o[2]=f2bf(a.z); o[3]=f2bf(a.w);
  o[4]=f2bf(b.x); o[5]=f2bf(b.y); o[6]=f2bf(b.z); o[7]=f2bf(b.w);
  ((bf16x8*)out)[i] = o;
}

// ---------------- pack weights transposed (B^T layout), bf16 ---------------
// WcatT [512][256]: row n<256 -> Wq[c][n]; n in [256,384) -> Wk[c][n-256];
//                   n in [384,512) -> Wv[c][n-384]
// WoutT [256][256]: WoutT[c][j] = Wout[j][c]
__global__ __launch_bounds__(256) void pack_w_kernel(const float* __restrict__ Wq,
                                                     const float* __restrict__ Wk,
                                                     const float* __restrict__ Wv,
                                                     const float* __restrict__ Wout,
                                                     short* __restrict__ WcatT,
                                                     short* __restrict__ WoutT) {
  int idx = blockIdx.x * 256 + threadIdx.x;
  if (idx < 512 * 256) {
    int n = idx >> 8, c = idx & 255;
    float val;
    if (n < 256)      val = Wq[c * 256 + n];
    else if (n < 384) val = Wk[c * 128 + (n - 256)];
    else              val = Wv[c * 128 + (n - 384)];
    WcatT[idx] = f2bf(val);
  } else {
    int j = idx - 512 * 256;           // 0..65535
    int cc = j >> 8, jj = j & 255;
    WoutT[j] = f2bf(Wout[jj * 256 + cc]);
  }
}

// ---------------- bf16 MFMA GEMM: C(M x N) = A(M x 256) * Bt(N x 256)^T ----
// 128x128 tile, 256 threads = 4 waves (2x2), each wave 64x64 via 4x4 16x16
// fragments. BK=64, reg-staged LDS, 2 barriers per K-step.
template <int N, bool OUTF32>
__global__ __launch_bounds__(256) void gemm_bf16(const short* __restrict__ A,
                                                 const short* __restrict__ Bt,
                                                 void* __restrict__ Cout) {
  __shared__ short As[128][64];
  __shared__ short Bs[128][64];
  const int tid = threadIdx.x;
  const int w = tid >> 6, ln = tid & 63;
  const int wr = (w >> 1) * 64, wc = (w & 1) * 64;
  const int bm = blockIdx.x * 128, bn = blockIdx.y * 128;
  const int lr = ln & 15, lk = (ln >> 4) * 8;
  const int r0 = tid >> 3, ko = (tid & 7) * 8;   // staging: row r0(+32..), 16B chunk ko

  f32x4 acc[4][4] = {};

  for (int k0 = 0; k0 < 256; k0 += 64) {
    // issue global loads early (latency overlaps previous compute)
    bf16x8 a0 = *(const bf16x8*)&A[(size_t)(bm + r0) * 256 + k0 + ko];
    bf16x8 a1 = *(const bf16x8*)&A[(size_t)(bm + 32 + r0) * 256 + k0 + ko];
    bf16x8 a2 = *(const bf16x8*)&A[(size_t)(bm + 64 + r0) * 256 + k0 + ko];
    bf16x8 a3 = *(const bf16x8*)&A[(size_t)(bm + 96 + r0) * 256 + k0 + ko];
    bf16x8 b0 = *(const bf16x8*)&Bt[(size_t)(bn + r0) * 256 + k0 + ko];
    bf16x8 b1 = *(const bf16x8*)&Bt[(size_t)(bn + 32 + r0) * 256 + k0 + ko];
    bf16x8 b2 = *(const bf16x8*)&Bt[(size_t)(bn + 64 + r0) * 256 + k0 + ko];
    bf16x8 b3 = *(const bf16x8*)&Bt[(size_t)(bn + 96 + r0) * 256 + k0 + ko];
    __syncthreads();   // previous iteration's fragment reads done
    *(bf16x8*)&As[r0][ko]      = a0;
    *(bf16x8*)&As[r0 + 32][ko] = a1;
    *(bf16x8*)&As[r0 + 64][ko] = a2;
    *(bf16x8*)&As[r0 + 96][ko] = a3;
    *(bf16x8*)&Bs[r0][ko]      = b0;
    *(bf16x8*)&Bs[r0 + 32][ko] = b1;
    *(bf16x8*)&Bs[r0 + 64][ko] = b2;
    *(bf16x8*)&Bs[r0 + 96][ko] = b3;
    __syncthreads();

#pragma unroll
    for (int kk = 0; kk < 2; ++kk) {
      bf16x8 af[4], bfr[4];
#pragma unroll
      for (int mi = 0; mi < 4; ++mi)
        af[mi] = *(const bf16x8*)&As[wr + mi * 16 + lr][kk * 32 + lk];
#pragma unroll
      for (int ni = 0; ni < 4; ++ni)
        bfr[ni] = *(const bf16x8*)&Bs[wc + ni * 16 + lr][kk * 32 + lk];
#pragma unroll
      for (int mi = 0; mi < 4; ++mi)
#pragma unroll
        for (int ni = 0; ni < 4; ++ni)
          acc[mi][ni] = __builtin_amdgcn_mfma_f32_16x16x32_bf16(af[mi], bfr[ni], acc[mi][ni], 0, 0, 0);
    }
  }

  const int rowg = (ln >> 4) * 4;
#pragma unroll
  for (int mi = 0; mi < 4; ++mi)
#pragma unroll
    for (int r = 0; r < 4; ++r) {
      size_t row = bm + wr + mi * 16 + rowg + r;
#pragma unroll
      for (int ni = 0; ni < 4; ++ni) {
        int col = bn + wc + ni * 16 + lr;
        if (OUTF32) ((float*)Cout)[row * N + col] = acc[mi][ni][r];
        else        ((short*)Cout)[row * N + col] = f2bf(acc[mi][ni][r]);
      }
    }
}

// ---------------- MFMA flash attention (bf16 in/out) -----------------------
// Block: (t-tile of 64, v*4+k, b). 4 waves; wave w owns t-rows t0+16w..+15
// for BOTH m heads. qkv row r=(b*T+t)*V+v, 512 bf16 cols:
// q at m*128+k*32+h, k at 256+k*32+h, v at 384+k*32+h.
__global__ __launch_bounds__(256) void attn_mfma(const short* __restrict__ qkv,
                                                 const int* __restrict__ mask,
                                                 short* __restrict__ att) {
  const int t0 = blockIdx.x * 64;
  const int v  = blockIdx.y >> 2;
  const int k  = blockIdx.y & 3;
  const int b  = blockIdx.z;
  const int tid = threadIdx.x;
  const int w  = tid >> 6;
  const int ln = tid & 63;
  const int gq = ln >> 4;
  const int tr = ln & 15;

  __shared__ short Kt[64][40];      // [s][h] pad 40
  __shared__ short Vt[32][72];      // [h][s] transposed, pad 72
  __shared__ short Pt[4][16][72];   // per-wave P tile [t][s], pad 72

  bf16x8 qf[2];
  {
    const short* qp = qkv + ((size_t)((b*TT + t0 + w*16 + tr)*VV + v))*512 + k*32 + gq*8;
    qf[0] = *(const bf16x8*)qp;
    qf[1] = *(const bf16x8*)(qp + 128);
  }

  f32x4 acc_o[2][2] = {};
  float m_run[2][4], l_run[2][4];
#pragma unroll
  for (int m = 0; m < 2; ++m)
#pragma unroll
    for (int r = 0; r < 4; ++r) { m_run[m][r] = -1e30f; l_run[m][r] = 0.f; }
  const float scale = 0.17677669529663687f;  // 1/sqrt(32)

  const int srow = tid >> 2;
  const int hg = (tid & 3) * 8;

  for (int s0 = 0; s0 < SS; s0 += 64) {
    __syncthreads();
    {
      const short* src = qkv + ((size_t)((b*TT + s0 + srow)*VV + v))*512 + 256 + k*32 + hg;
      bf16x8 kv = *(const bf16x8*)src;
      bf16x8 vv = *(const bf16x8*)(src + 128);
      *(bf16x8*)&Kt[srow][hg] = kv;
#pragma unroll
      for (int j = 0; j < 8; ++j) Vt[hg + j][srow] = vv[j];
    }
    __syncthreads();

    bf16x8 kf[4], vf[2][2];
#pragma unroll
    for (int st = 0; st < 4; ++st) kf[st] = *(const bf16x8*)&Kt[st*16 + tr][gq*8];
#pragma unroll
    for (int sh = 0; sh < 2; ++sh)
#pragma unroll
      for (int hh = 0; hh < 2; ++hh)
        vf[sh][hh] = *(const bf16x8*)&Vt[hh*16 + tr][sh*32 + gq*8];

    f32x4 lac[2][4];
#pragma unroll
    for (int m = 0; m < 2; ++m)
#pragma unroll
      for (int st = 0; st < 4; ++st) {
        f32x4 z = {0.f, 0.f, 0.f, 0.f};
        lac[m][st] = __builtin_amdgcn_mfma_f32_16x16x32_bf16(qf[m], kf[st], z, 0, 0, 0);
      }

    int msk[4][4];
    {
      const int* mrow = mask + ((size_t)(b*TT + t0 + w*16 + 4*gq))*SS + s0 + tr;
#pragma unroll
      for (int r = 0; r < 4; ++r)
#pragma unroll
        for (int st = 0; st < 4; ++st)
          msk[st][r] = mrow[(size_t)r*SS + st*16];
    }

#pragma unroll
    for (int m = 0; m < 2; ++m) {
      float pl[4][4];
#pragma unroll
      for (int st = 0; st < 4; ++st)
#pragma unroll
        for (int r = 0; r < 4; ++r)
          pl[st][r] = msk[st][r] ? lac[m][st][r] * scale : -INFINITY;

      float cm[4], mnew[4], corr[4], rs[4];
#pragma unroll
      for (int r = 0; r < 4; ++r) {
        cm[r] = fmaxf(fmaxf(pl[0][r], pl[1][r]), fmaxf(pl[2][r], pl[3][r]));
#pragma unroll
        for (int off = 1; off < 16; off <<= 1) cm[r] = fmaxf(cm[r], __shfl_xor(cm[r], off));
        mnew[r] = fmaxf(m_run[m][r], cm[r]);
        corr[r] = __expf(m_run[m][r] - mnew[r]);
      }
#pragma unroll
      for (int st = 0; st < 4; ++st)
#pragma unroll
        for (int r = 0; r < 4; ++r)
          pl[st][r] = __expf(pl[st][r] - mnew[r]);
#pragma unroll
      for (int r = 0; r < 4; ++r) {
        rs[r] = pl[0][r] + pl[1][r] + pl[2][r] + pl[3][r];
#pragma unroll
        for (int off = 1; off < 16; off <<= 1) rs[r] += __shfl_xor(rs[r], off);
        l_run[m][r] = l_run[m][r] * corr[r] + rs[r];
        m_run[m][r] = mnew[r];
      }
#pragma unroll
      for (int hh = 0; hh < 2; ++hh)
#pragma unroll
        for (int r = 0; r < 4; ++r)
          acc_o[m][hh][r] *= corr[r];

#pragma unroll
      for (int st = 0; st < 4; ++st)
#pragma unroll
        for (int r = 0; r < 4; ++r)
          Pt[w][4*gq + r][st*16 + tr] = f2bf(pl[st][r]);
#pragma unroll
      for (int sh = 0; sh < 2; ++sh) {
        bf16x8 pf = *(const bf16x8*)&Pt[w][tr][sh*32 + gq*8];
#pragma unroll
        for (int hh = 0; hh < 2; ++hh)
          acc_o[m][hh] = __builtin_amdgcn_mfma_f32_16x16x32_bf16(pf, vf[sh][hh], acc_o[m][hh], 0, 0, 0);
      }
    }
  }

#pragma unroll
  for (int m = 0; m < 2; ++m)
#pragma unroll
    for (int r = 0; r < 4; ++r) {
      float inv = 1.f / l_run[m][r];
      short* dst = att + ((size_t)((b*TT + t0 + w*16 + 4*gq + r)*VV + v))*256
                 + m*128 + k*32 + tr;
      dst[0]  = f2bf(acc_o[m][0][r] * inv);
      dst[16] = f2bf(acc_o[m][1][r] * inv);
    }
}

extern "C" void kernel_launch(void* const* d_in, const int* in_sizes, int n_in,
                              void* d_out, int out_size, void* d_ws, size_t ws_size,
                              hipStream_t stream) {
  const float* x = (const float*)d_in[0];
  const float* Wq = (const float*)d_in[1];
  const float* Wk = (const float*)d_in[2];
  const float* Wv = (const float*)d_in[3];
  const float* Wout = (const float*)d_in[4];
  const int* mask = (const int*)d_in[5];
  float* out = (float*)d_out;

  // ws layout (bf16 elements)
  short* xb    = (short*)d_ws;                    // 16384*256
  short* WcatT = xb + (size_t)NROWS * 256;        // 512*256
  short* WoutT = WcatT + 512 * 256;               // 256*256
  short* qkv   = WoutT + 256 * 256;               // 16384*512
  short* att   = qkv + (size_t)NROWS * 512;       // 16384*256
  // total ~33 MB

  cvt_bf16_kernel<<<NROWS * 256 / 8 / 256, 256, 0, stream>>>(x, xb);
  pack_w_kernel<<<(512 * 256 + 256 * 256) / 256, 256, 0, stream>>>(Wq, Wk, Wv, Wout, WcatT, WoutT);
  gemm_bf16<512, false><<<dim3(NROWS / 128, 4), 256, 0, stream>>>(xb, WcatT, qkv);
  attn_mfma<<<dim3(TT / 64, VV * 4, BB), 256, 0, stream>>>(qkv, mask, att);
  gemm_bf16<256, true><<<dim3(NROWS / 128, 2), 256, 0, stream>>>(att, WoutT, out);
}

// Round 4
// 72.811 us; speedup vs baseline: 5.8146x; 1.2640x over previous
//
#include <hip/hip_runtime.h>
#include <hip/hip_bf16.h>
#include <cstdint>

// Problem constants: B=4, T=512, S=512, V=8, M=2, K=4, F=1, Hqk=32, Hv=32, C=256
#define BB 4
#define TT 512
#define SS 512
#define VV 8
#define NROWS (BB * TT * VV)   // 16384

typedef __attribute__((ext_vector_type(8))) short bf16x8;
typedef __attribute__((ext_vector_type(4))) float f32x4;

static __device__ __forceinline__ short f2bf(float f) {
  union { float f; unsigned u; } x; x.f = f;
  unsigned r = x.u + 0x7FFFu + ((x.u >> 16) & 1u);  // RNE
  return (short)(r >> 16);
}

// ---------------- fp32 -> bf16 bulk convert (8 elems/thread) ---------------
__global__ __launch_bounds__(256) void cvt_bf16_kernel(const float* __restrict__ in,
                                                       short* __restrict__ out) {
  int i = blockIdx.x * 256 + threadIdx.x;
  float4 a = ((const float4*)in)[2 * i];
  float4 b = ((const float4*)in)[2 * i + 1];
  bf16x8 o;
  o[0]=f2bf(a.x); o[1]=f2bf(a.y); o[2]=f2bf(a.z); o[3]=f2bf(a.w);
  o[4]=f2bf(b.x); o[5]=f2bf(b.y); o[6]=f2bf(b.z); o[7]=f2bf(b.w);
  ((bf16x8*)out)[i] = o;
}

// ---------------- pack weights transposed (B^T layout), bf16 ---------------
// WcatT [512][256]; q-rows (n<256) pre-scaled by 1/sqrt(32) so attention
// logits come out of the MFMA already scaled.
__global__ __launch_bounds__(256) void pack_w_kernel(const float* __restrict__ Wq,
                                                     const float* __restrict__ Wk,
                                                     const float* __restrict__ Wv,
                                                     const float* __restrict__ Wout,
                                                     short* __restrict__ WcatT,
                                                     short* __restrict__ WoutT) {
  int idx = blockIdx.x * 256 + threadIdx.x;
  if (idx < 512 * 256) {
    int n = idx >> 8, c = idx & 255;
    float val;
    if (n < 256)      val = Wq[c * 256 + n] * 0.17677669529663687f;  // fold 1/sqrt(32)
    else if (n < 384) val = Wk[c * 128 + (n - 256)];
    else              val = Wv[c * 128 + (n - 384)];
    WcatT[idx] = f2bf(val);
  } else {
    int j = idx - 512 * 256;
    int cc = j >> 8, jj = j & 255;
    WoutT[j] = f2bf(Wout[jj * 256 + cc]);
  }
}

// ---------------- pack mask to bits: mask64[row][c] bit j = mask[row][c*64+j]
__global__ __launch_bounds__(256) void pack_mask_kernel(const int* __restrict__ mask,
                                                        unsigned long long* __restrict__ mask64) {
  int row = blockIdx.x * 4 + (threadIdx.x >> 6);   // one wave per (b,t) row
  int ln = threadIdx.x & 63;
  const int* mrow = mask + (size_t)row * SS;
#pragma unroll
  for (int c = 0; c < 8; ++c) {
    unsigned long long bal = __ballot(mrow[c * 64 + ln] != 0);
    if (ln == 0) mask64[(size_t)row * 8 + c] = bal;
  }
}

// ---------------- bf16 MFMA GEMM: C(M x N) = A(M x 256) * Bt(N x 256)^T ----
template <int N, bool OUTF32>
__global__ __launch_bounds__(256) void gemm_bf16(const short* __restrict__ A,
                                                 const short* __restrict__ Bt,
                                                 void* __restrict__ Cout) {
  __shared__ short As[128][64];
  __shared__ short Bs[128][64];
  const int tid = threadIdx.x;
  const int w = tid >> 6, ln = tid & 63;
  const int wr = (w >> 1) * 64, wc = (w & 1) * 64;
  const int bm = blockIdx.x * 128, bn = blockIdx.y * 128;
  const int lr = ln & 15, lk = (ln >> 4) * 8;
  const int r0 = tid >> 3, ko = (tid & 7) * 8;

  f32x4 acc[4][4] = {};

  for (int k0 = 0; k0 < 256; k0 += 64) {
    bf16x8 a0 = *(const bf16x8*)&A[(size_t)(bm + r0) * 256 + k0 + ko];
    bf16x8 a1 = *(const bf16x8*)&A[(size_t)(bm + 32 + r0) * 256 + k0 + ko];
    bf16x8 a2 = *(const bf16x8*)&A[(size_t)(bm + 64 + r0) * 256 + k0 + ko];
    bf16x8 a3 = *(const bf16x8*)&A[(size_t)(bm + 96 + r0) * 256 + k0 + ko];
    bf16x8 b0 = *(const bf16x8*)&Bt[(size_t)(bn + r0) * 256 + k0 + ko];
    bf16x8 b1 = *(const bf16x8*)&Bt[(size_t)(bn + 32 + r0) * 256 + k0 + ko];
    bf16x8 b2 = *(const bf16x8*)&Bt[(size_t)(bn + 64 + r0) * 256 + k0 + ko];
    bf16x8 b3 = *(const bf16x8*)&Bt[(size_t)(bn + 96 + r0) * 256 + k0 + ko];
    __syncthreads();
    *(bf16x8*)&As[r0][ko]      = a0;
    *(bf16x8*)&As[r0 + 32][ko] = a1;
    *(bf16x8*)&As[r0 + 64][ko] = a2;
    *(bf16x8*)&As[r0 + 96][ko] = a3;
    *(bf16x8*)&Bs[r0][ko]      = b0;
    *(bf16x8*)&Bs[r0 + 32][ko] = b1;
    *(bf16x8*)&Bs[r0 + 64][ko] = b2;
    *(bf16x8*)&Bs[r0 + 96][ko] = b3;
    __syncthreads();

#pragma unroll
    for (int kk = 0; kk < 2; ++kk) {
      bf16x8 af[4], bfr[4];
#pragma unroll
      for (int mi = 0; mi < 4; ++mi)
        af[mi] = *(const bf16x8*)&As[wr + mi * 16 + lr][kk * 32 + lk];
#pragma unroll
      for (int ni = 0; ni < 4; ++ni)
        bfr[ni] = *(const bf16x8*)&Bs[wc + ni * 16 + lr][kk * 32 + lk];
#pragma unroll
      for (int mi = 0; mi < 4; ++mi)
#pragma unroll
        for (int ni = 0; ni < 4; ++ni)
          acc[mi][ni] = __builtin_amdgcn_mfma_f32_16x16x32_bf16(af[mi], bfr[ni], acc[mi][ni], 0, 0, 0);
    }
  }

  const int rowg = (ln >> 4) * 4;
#pragma unroll
  for (int mi = 0; mi < 4; ++mi)
#pragma unroll
    for (int r = 0; r < 4; ++r) {
      size_t row = bm + wr + mi * 16 + rowg + r;
#pragma unroll
      for (int ni = 0; ni < 4; ++ni) {
        int col = bn + wc + ni * 16 + lr;
        if (OUTF32) ((float*)Cout)[row * N + col] = acc[mi][ni][r];
        else        ((short*)Cout)[row * N + col] = f2bf(acc[mi][ni][r]);
      }
    }
}

// ---------------- MFMA flash attention, swapped-QK^T ----------------------
// Block: (t-tile 64, v*4+k, b); wave w owns t-rows t0+16w..+15, both m heads.
// Swapped QK^T: lac = mfma(K,Q) -> D[s][t] with col t=tr, row s=st*16+4gq+r.
// Softmax state per lane for t=tr (4 consistent copies across gq groups).
__global__ __launch_bounds__(256) void attn_mfma(const short* __restrict__ qkv,
                                                 const unsigned long long* __restrict__ mask64,
                                                 short* __restrict__ att) {
  const int t0 = blockIdx.x * 64;
  const int v  = blockIdx.y >> 2;
  const int k  = blockIdx.y & 3;
  const int b  = blockIdx.z;
  const int tid = threadIdx.x;
  const int w  = tid >> 6;
  const int ln = tid & 63;
  const int gq = ln >> 4;
  const int tr = ln & 15;

  __shared__ short Kt[2][64][40];   // [buf][s][h] pad 40
  __shared__ short Vt[2][32][72];   // [buf][h][s] transposed, pad 72
  __shared__ short Pt[4][16][72];   // per-wave P [t][s], pad 72

  bf16x8 qf[2];  // Q pre-scaled (folded into Wq)
  {
    const short* qp = qkv + ((size_t)((b*TT + t0 + w*16 + tr)*VV + v))*512 + k*32 + gq*8;
    qf[0] = *(const bf16x8*)qp;
    qf[1] = *(const bf16x8*)(qp + 128);
  }

  f32x4 acc_o[2][2] = {};            // [m][h-half], row t=4gq+r, col h=hh*16+tr
  float m_run[2] = {-1e30f, -1e30f}; // per lane: t = tr
  float l_run[2] = {0.f, 0.f};

  const int srow = tid >> 2;
  const int hg = (tid & 3) * 8;
  const unsigned long long* mrow = mask64 + ((size_t)(b*TT + t0 + w*16 + tr)) * 8;

  // prologue: chunk 0 -> regs
  const short* src0 = qkv + ((size_t)((b*TT + srow)*VV + v))*512 + 256 + k*32 + hg;
  bf16x8 kreg = *(const bf16x8*)src0;
  bf16x8 vreg = *(const bf16x8*)(src0 + 128);

  for (int c = 0; c < 8; ++c) {
    const int cur = c & 1;
    // write staged regs to LDS (buffer cur)
    *(bf16x8*)&Kt[cur][srow][hg] = kreg;
#pragma unroll
    for (int j = 0; j < 8; ++j) Vt[cur][hg + j][srow] = vreg[j];
    __syncthreads();
    // issue next chunk's global loads (hide under compute)
    if (c < 7) {
      const short* src = qkv + ((size_t)((b*TT + (c + 1) * 64 + srow)*VV + v))*512 + 256 + k*32 + hg;
      kreg = *(const bf16x8*)src;
      vreg = *(const bf16x8*)(src + 128);
    }
    // mask bits: one 8B load covers all 64 s for this lane's t
    unsigned long long mb = mrow[c];
    unsigned mlo = (unsigned)mb, mhi = (unsigned)(mb >> 32);
    float bias[4][4];
#pragma unroll
    for (int st = 0; st < 4; ++st) {
      unsigned wbits = (st < 2) ? mlo : mhi;
      const int base = (st & 1) * 16 + 4 * gq;
#pragma unroll
      for (int r = 0; r < 4; ++r)
        bias[st][r] = ((wbits >> (base + r)) & 1u) ? 0.f : -INFINITY;
    }

    bf16x8 kf[4], vf[2][2];
#pragma unroll
    for (int st = 0; st < 4; ++st) kf[st] = *(const bf16x8*)&Kt[cur][st*16 + tr][gq*8];
#pragma unroll
    for (int sh = 0; sh < 2; ++sh)
#pragma unroll
      for (int hh = 0; hh < 2; ++hh)
        vf[sh][hh] = *(const bf16x8*)&Vt[cur][hh*16 + tr][sh*32 + gq*8];

#pragma unroll
    for (int m = 0; m < 2; ++m) {
      // swapped QK^T: D[s][t]
      f32x4 lac[4];
#pragma unroll
      for (int st = 0; st < 4; ++st) {
        f32x4 z = {0.f, 0.f, 0.f, 0.f};
        lac[st] = __builtin_amdgcn_mfma_f32_16x16x32_bf16(kf[st], qf[m], z, 0, 0, 0);
      }
      float pl[4][4];
#pragma unroll
      for (int st = 0; st < 4; ++st)
#pragma unroll
        for (int r = 0; r < 4; ++r)
          pl[st][r] = lac[st][r] + bias[st][r];

      // column max: 15 in-lane + 2 shfl
      float cm = -INFINITY;
#pragma unroll
      for (int st = 0; st < 4; ++st)
#pragma unroll
        for (int r = 0; r < 4; ++r) cm = fmaxf(cm, pl[st][r]);
      cm = fmaxf(cm, __shfl_xor(cm, 16));
      cm = fmaxf(cm, __shfl_xor(cm, 32));

      // defer-max (THR=8): skip rescale when max growth is small
      bool skip = __all(cm - m_run[m] <= 8.f);
      float mnew, corr;
      if (skip) { mnew = m_run[m]; corr = 1.f; }
      else {
        mnew = fmaxf(m_run[m], cm);
        corr = __expf(m_run[m] - mnew);
        m_run[m] = mnew;
      }

      float rs = 0.f;
#pragma unroll
      for (int st = 0; st < 4; ++st)
#pragma unroll
        for (int r = 0; r < 4; ++r) {
          pl[st][r] = __expf(pl[st][r] - mnew);   // masked: exp(-inf)=0
          rs += pl[st][r];
        }
      rs += __shfl_xor(rs, 16);
      rs += __shfl_xor(rs, 32);
      l_run[m] = l_run[m] * corr + rs;

      if (!skip) {
        float corrR[4];
#pragma unroll
        for (int r = 0; r < 4; ++r) corrR[r] = __shfl(corr, 4 * gq + r);
#pragma unroll
        for (int hh = 0; hh < 2; ++hh)
#pragma unroll
          for (int r = 0; r < 4; ++r) acc_o[m][hh][r] *= corrR[r];
      }

      // P write: 4 consecutive s per (st) -> 2 packed dwords, ds_write_b64
#pragma unroll
      for (int st = 0; st < 4; ++st) {
        unsigned d0 = ((unsigned)(unsigned short)f2bf(pl[st][1]) << 16) |
                      (unsigned)(unsigned short)f2bf(pl[st][0]);
        unsigned d1 = ((unsigned)(unsigned short)f2bf(pl[st][3]) << 16) |
                      (unsigned)(unsigned short)f2bf(pl[st][2]);
        *(uint2*)&Pt[w][tr][st * 16 + 4 * gq] = make_uint2(d0, d1);
      }
      // PV (wave-local LDS write->read; compiler inserts lgkmcnt)
#pragma unroll
      for (int sh = 0; sh < 2; ++sh) {
        bf16x8 pf = *(const bf16x8*)&Pt[w][tr][sh * 32 + gq * 8];
#pragma unroll
        for (int hh = 0; hh < 2; ++hh)
          acc_o[m][hh] = __builtin_amdgcn_mfma_f32_16x16x32_bf16(pf, vf[sh][hh], acc_o[m][hh], 0, 0, 0);
      }
    }
  }

  // epilogue: acc row t=4gq+r needs l for that t (held by lane 4gq+r)
#pragma unroll
  for (int m = 0; m < 2; ++m) {
    float invR[4];
#pragma unroll
    for (int r = 0; r < 4; ++r) invR[r] = 1.f / __shfl(l_run[m], 4 * gq + r);
#pragma unroll
    for (int r = 0; r < 4; ++r) {
      short* dst = att + ((size_t)((b*TT + t0 + w*16 + 4*gq + r)*VV + v))*256
                 + m*128 + k*32 + tr;
      dst[0]  = f2bf(acc_o[m][0][r] * invR[r]);
      dst[16] = f2bf(acc_o[m][1][r] * invR[r]);
    }
  }
}

extern "C" void kernel_launch(void* const* d_in, const int* in_sizes, int n_in,
                              void* d_out, int out_size, void* d_ws, size_t ws_size,
                              hipStream_t stream) {
  const float* x = (const float*)d_in[0];
  const float* Wq = (const float*)d_in[1];
  const float* Wk = (const float*)d_in[2];
  const float* Wv = (const float*)d_in[3];
  const float* Wout = (const float*)d_in[4];
  const int* mask = (const int*)d_in[5];
  float* out = (float*)d_out;

  // ws layout (bf16 elements unless noted)
  short* xb    = (short*)d_ws;                    // 16384*256
  short* WcatT = xb + (size_t)NROWS * 256;        // 512*256
  short* WoutT = WcatT + 512 * 256;               // 256*256
  short* qkv   = WoutT + 256 * 256;               // 16384*512
  short* att   = qkv + (size_t)NROWS * 512;       // 16384*256
  unsigned long long* mask64 = (unsigned long long*)(att + (size_t)NROWS * 256); // 2048*8 ull

  cvt_bf16_kernel<<<NROWS * 256 / 8 / 256, 256, 0, stream>>>(x, xb);
  pack_w_kernel<<<(512 * 256 + 256 * 256) / 256, 256, 0, stream>>>(Wq, Wk, Wv, Wout, WcatT, WoutT);
  pack_mask_kernel<<<BB * TT / 4, 256, 0, stream>>>(mask, mask64);
  gemm_bf16<512, false><<<dim3(NROWS / 128, 4), 256, 0, stream>>>(xb, WcatT, qkv);
  attn_mfma<<<dim3(TT / 64, VV * 4, BB), 256, 0, stream>>>(qkv, mask64, att);
  gemm_bf16<256, true><<<dim3(NROWS / 128, 2), 256, 0, stream>>>(att, WoutT, out);
}